// Round 1
// baseline (2076.348 us; speedup 1.0000x reference)
//
#include <hip/hip_runtime.h>
#include <stdint.h>

#define NEDGE 500000
#define NUSR  100000
#define NENT  200000

typedef unsigned short u16;

__device__ __forceinline__ float bf2f(u16 h){
  unsigned int u = ((unsigned int)h) << 16; float f;
  __builtin_memcpy(&f, &u, 4); return f;
}
__device__ __forceinline__ u16 f2bf(float f){
  unsigned int u; __builtin_memcpy(&u, &f, 4);
  u = (u + 0x7fffu + ((u >> 16) & 1u)) >> 16;
  return (u16)u;
}

// ---------------------------------------------------------------------------
// Pass 1: per-edge relation_ui matvec (f32), argmax -> rel_type, bf16 relation
// store, first-level scatter sums (sum_ne by (factor,user), sum_up by item).
// Block: 256 threads, 64 edges. Thread (og,eg) owns edges {eg+16i}, outs {og+16j}.
// ---------------------------------------------------------------------------
__global__ __launch_bounds__(256,2) void k_pass1(
    const float* __restrict__ ent, const float* __restrict__ usr,
    const float* __restrict__ lat,
    const int* __restrict__ uidx, const int* __restrict__ iidx,
    const float* __restrict__ Ww, const float* __restrict__ Wb,
    float* __restrict__ sum_ne, float* __restrict__ cnt,
    float* __restrict__ sum_up, float* __restrict__ cnt_i,
    int* __restrict__ rtype, u16* __restrict__ rel16)
{
  __shared__ __align__(16) float w_lds[64*132];   // W rows padded (bank stagger)
  __shared__ __align__(16) float in_lds[64*132];  // [up|ip] rows padded
  __shared__ float lat_lds[192];
  __shared__ float b_lds[64];
  __shared__ int ui_s[64], ii_s[64], f_s[64];
  __shared__ __align__(16) u16 relbuf[64*64];     // bf16 relation; reused as score partials

  const int t  = threadIdx.x;
  const int e0 = blockIdx.x * 64;

  // A: stage W (64x128), bias, latent, edge indices
  #pragma unroll
  for (int r = 0; r < 8; r++){
    int g = t + 256*r; int row = g >> 5, c4 = (g & 31) << 2;
    *(float4*)&w_lds[row*132 + c4] = *(const float4*)(Ww + row*128 + c4);
  }
  if (t < 192) lat_lds[t] = lat[t];
  if (t < 64){
    b_lds[t] = Wb[t];
    int e = e0 + t;
    ui_s[t] = (e < NEDGE) ? uidx[e] : 0;
    ii_s[t] = (e < NEDGE) ? iidx[e] : 0;
  }
  __syncthreads();

  // B: gather concat([user_pair, item_pair]) rows
  #pragma unroll
  for (int r = 0; r < 8; r++){
    int g = t + 256*r; int e = g >> 5, c = g & 31;
    float4 v;
    if (e0 + e < NEDGE){
      const float* src = (c < 16) ? (usr + (size_t)ui_s[e]*64 + (c << 2))
                                  : (ent + (size_t)ii_s[e]*64 + ((c-16) << 2));
      v = *(const float4*)src;
    } else v = make_float4(0.f,0.f,0.f,0.f);
    *(float4*)&in_lds[e*132 + (c << 2)] = v;
  }
  __syncthreads();

  // C: 128->64 matvec, 4 edges x 4 outs per thread
  const int og = t >> 4, eg = t & 15;
  float acc[4][4];
  #pragma unroll
  for (int i = 0; i < 4; i++)
    #pragma unroll
    for (int j = 0; j < 4; j++) acc[i][j] = b_lds[og + 16*j];
  for (int k = 0; k < 128; k += 4){
    float4 av[4], wv[4];
    #pragma unroll
    for (int i = 0; i < 4; i++) av[i] = *(const float4*)&in_lds[(eg+16*i)*132 + k];
    #pragma unroll
    for (int j = 0; j < 4; j++) wv[j] = *(const float4*)&w_lds[(og+16*j)*132 + k];
    #pragma unroll
    for (int i = 0; i < 4; i++)
      #pragma unroll
      for (int j = 0; j < 4; j++)
        acc[i][j] += av[i].x*wv[j].x + av[i].y*wv[j].y + av[i].z*wv[j].z + av[i].w*wv[j].w;
  }
  #pragma unroll
  for (int i = 0; i < 4; i++)
    #pragma unroll
    for (int j = 0; j < 4; j++){
      float v = acc[i][j];
      acc[i][j] = v > 0.f ? v : 0.01f*v;   // leaky_relu(0.01), matches jax default
    }

  // D1: relation -> LDS as bf16
  #pragma unroll
  for (int i = 0; i < 4; i++)
    #pragma unroll
    for (int j = 0; j < 4; j++)
      relbuf[(eg+16*i)*64 + og + 16*j] = f2bf(acc[i][j]);
  __syncthreads();

  // D2: coalesced global bf16 store + f32 score partials (vs latent)
  #pragma unroll
  for (int r = 0; r < 4; r++){
    int g = t + 256*r; int e = g >> 4, c = g & 15;
    if (e0 + e < NEDGE)
      *(ushort4*)(rel16 + (size_t)(e0+e)*64 + (c << 2)) =
          *(const ushort4*)&relbuf[e*64 + (c << 2)];
  }
  float p[4][3];
  #pragma unroll
  for (int i = 0; i < 4; i++)
    #pragma unroll
    for (int f = 0; f < 3; f++){
      float s = 0.f;
      #pragma unroll
      for (int j = 0; j < 4; j++) s += acc[i][j] * lat_lds[f*64 + og + 16*j];
      s += __shfl_xor(s, 16);
      s += __shfl_xor(s, 32);
      p[i][f] = s;
    }
  __syncthreads();                       // relbuf reads complete

  float* part = (float*)relbuf;          // [wave][edge][factor] partials (3 KB < 8 KB)
  if ((t & 63) < 16){
    int wv = t >> 6;
    #pragma unroll
    for (int i = 0; i < 4; i++)
      #pragma unroll
      for (int f = 0; f < 3; f++)
        part[(wv*64 + eg + 16*i)*3 + f] = p[i][f];
  }
  __syncthreads();

  if (t < 64){
    int bf = 0;
    if (e0 + t < NEDGE){
      float s0 = part[t*3+0] + part[(64+t)*3+0] + part[(128+t)*3+0] + part[(192+t)*3+0];
      float s1 = part[t*3+1] + part[(64+t)*3+1] + part[(128+t)*3+1] + part[(192+t)*3+1];
      float s2 = part[t*3+2] + part[(64+t)*3+2] + part[(128+t)*3+2] + part[(192+t)*3+2];
      float bs = s0;
      if (s1 > bs){ bs = s1; bf = 1; }   // strict > : first-max ties like jnp.argmax
      if (s2 > bs){ bs = s2; bf = 2; }
      rtype[e0 + t] = bf;
    }
    f_s[t] = bf;
  }
  __syncthreads();

  // E: scatter atomics (user_pair -> sum_up[item]; item_pair -> sum_ne[f][user])
  #pragma unroll
  for (int r = 0; r < 8; r++){
    int g = t + 256*r; int e = g >> 5, c = g & 31;
    if (e0 + e >= NEDGE) continue;
    float4 v = *(const float4*)&in_lds[e*132 + (c << 2)];
    if (c < 16){
      float* dst = sum_up + (size_t)ii_s[e]*64 + (c << 2);
      atomicAdd(dst+0, v.x); atomicAdd(dst+1, v.y);
      atomicAdd(dst+2, v.z); atomicAdd(dst+3, v.w);
      if (c == 0) atomicAdd(cnt_i + ii_s[e], 1.0f);
    } else {
      size_t base = ((size_t)f_s[e]*NUSR + ui_s[e])*64;
      float* dst = sum_ne + base + ((c-16) << 2);
      atomicAdd(dst+0, v.x); atomicAdd(dst+1, v.y);
      atomicAdd(dst+2, v.z); atomicAdd(dst+3, v.w);
      if (c == 16) atomicAdd(cnt + (size_t)f_s[e]*NUSR + ui_s[e], 1.0f);
    }
  }
}

// ---------------------------------------------------------------------------
// Pass 2a (user side): sim = dot(rel_ui, sum_ne[f][u]) / denom; acc2 += sim*ip.
// 16 lanes per edge, no LDS.
// ---------------------------------------------------------------------------
__global__ __launch_bounds__(256) void k_pass2_user(
    const float* __restrict__ ent,
    const int* __restrict__ uidx, const int* __restrict__ iidx,
    const float* __restrict__ sum_ne, const float* __restrict__ cnt,
    const int* __restrict__ rtype, const u16* __restrict__ rel16,
    float* __restrict__ acc2)
{
  const int t = threadIdx.x;
  const int lane = t & 63;
  const int e = blockIdx.x*16 + (t >> 6)*4 + (lane >> 4);
  if (e >= NEDGE) return;
  const int c  = lane & 15;
  const int f  = rtype[e];
  const int u  = uidx[e];
  const int it = iidx[e];
  ushort4 rh = *(const ushort4*)(rel16 + (size_t)e*64 + (c << 2));
  size_t rbase = ((size_t)f*NUSR + u)*64;
  float4 sv = *(const float4*)(sum_ne + rbase + (c << 2));
  float ps = bf2f(rh.x)*sv.x + bf2f(rh.y)*sv.y + bf2f(rh.z)*sv.z + bf2f(rh.w)*sv.w;
  ps += __shfl_xor(ps, 1); ps += __shfl_xor(ps, 2);
  ps += __shfl_xor(ps, 4); ps += __shfl_xor(ps, 8);
  float sim = ps / fmaxf(cnt[(size_t)f*NUSR + u], 1.0f);   // dot(u_)/denom folded
  float4 ip = *(const float4*)(ent + (size_t)it*64 + (c << 2));
  float* dst = acc2 + rbase + (c << 2);
  atomicAdd(dst+0, sim*ip.x); atomicAdd(dst+1, sim*ip.y);
  atomicAdd(dst+2, sim*ip.z); atomicAdd(dst+3, sim*ip.w);
}

// ---------------------------------------------------------------------------
// Pass 2b (entity side): relation_iu matvec (f32, computed once, not stored),
// sim_i vs gathered y-row, scatter sim_i * user_pair into d_out entity region.
// ---------------------------------------------------------------------------
__global__ __launch_bounds__(256,2) void k_pass2_ent(
    const float* __restrict__ ent, const float* __restrict__ usr,
    const int* __restrict__ uidx, const int* __restrict__ iidx,
    const float* __restrict__ Wiw, const float* __restrict__ Wib,
    const float* __restrict__ sum_up, const float* __restrict__ cnt_i,
    float* __restrict__ out_ent)
{
  __shared__ __align__(16) float w_lds[64*132];
  __shared__ __align__(16) float in_lds[64*132];  // [ip|up] (concat order flipped!)
  __shared__ float b_lds[64];
  __shared__ int ui_s[64], ii_s[64];
  __shared__ __align__(8) u16 y_lds[64*68];       // bf16 y rows (continuous use only)
  __shared__ float part[4*64];
  __shared__ float sim_s[64];

  const int t  = threadIdx.x;
  const int e0 = blockIdx.x * 64;

  #pragma unroll
  for (int r = 0; r < 8; r++){
    int g = t + 256*r; int row = g >> 5, c4 = (g & 31) << 2;
    *(float4*)&w_lds[row*132 + c4] = *(const float4*)(Wiw + row*128 + c4);
  }
  if (t < 64){
    b_lds[t] = Wib[t];
    int e = e0 + t;
    ui_s[t] = (e < NEDGE) ? uidx[e] : 0;
    ii_s[t] = (e < NEDGE) ? iidx[e] : 0;
  }
  __syncthreads();

  #pragma unroll
  for (int r = 0; r < 8; r++){
    int g = t + 256*r; int e = g >> 5, c = g & 31;
    float4 v;
    if (e0 + e < NEDGE){
      const float* src = (c < 16) ? (ent + (size_t)ii_s[e]*64 + (c << 2))
                                  : (usr + (size_t)ui_s[e]*64 + ((c-16) << 2));
      v = *(const float4*)src;
    } else v = make_float4(0.f,0.f,0.f,0.f);
    *(float4*)&in_lds[e*132 + (c << 2)] = v;
  }
  #pragma unroll
  for (int r = 0; r < 4; r++){
    int g = t + 256*r; int e = g >> 4, c = g & 15;
    float4 v;
    if (e0 + e < NEDGE) v = *(const float4*)(sum_up + (size_t)ii_s[e]*64 + (c << 2));
    else v = make_float4(0.f,0.f,0.f,0.f);
    ushort4 h; h.x = f2bf(v.x); h.y = f2bf(v.y); h.z = f2bf(v.z); h.w = f2bf(v.w);
    *(ushort4*)&y_lds[e*68 + (c << 2)] = h;
  }
  __syncthreads();

  const int og = t >> 4, eg = t & 15;
  float acc[4][4];
  #pragma unroll
  for (int i = 0; i < 4; i++)
    #pragma unroll
    for (int j = 0; j < 4; j++) acc[i][j] = b_lds[og + 16*j];
  for (int k = 0; k < 128; k += 4){
    float4 av[4], wv[4];
    #pragma unroll
    for (int i = 0; i < 4; i++) av[i] = *(const float4*)&in_lds[(eg+16*i)*132 + k];
    #pragma unroll
    for (int j = 0; j < 4; j++) wv[j] = *(const float4*)&w_lds[(og+16*j)*132 + k];
    #pragma unroll
    for (int i = 0; i < 4; i++)
      #pragma unroll
      for (int j = 0; j < 4; j++)
        acc[i][j] += av[i].x*wv[j].x + av[i].y*wv[j].y + av[i].z*wv[j].z + av[i].w*wv[j].w;
  }
  #pragma unroll
  for (int i = 0; i < 4; i++)
    #pragma unroll
    for (int j = 0; j < 4; j++){
      float v = acc[i][j];
      acc[i][j] = v > 0.f ? v : 0.01f*v;
    }

  float p[4];
  #pragma unroll
  for (int i = 0; i < 4; i++){
    float s = 0.f;
    #pragma unroll
    for (int j = 0; j < 4; j++)
      s += acc[i][j] * bf2f(y_lds[(eg+16*i)*68 + og + 16*j]);
    s += __shfl_xor(s, 16);
    s += __shfl_xor(s, 32);
    p[i] = s;
  }
  if ((t & 63) < 16){
    int wv = t >> 6;
    #pragma unroll
    for (int i = 0; i < 4; i++) part[wv*64 + eg + 16*i] = p[i];
  }
  __syncthreads();
  if (t < 64){
    float S = part[t] + part[64+t] + part[128+t] + part[192+t];
    sim_s[t] = (e0 + t < NEDGE) ? S / fmaxf(cnt_i[ii_s[t]], 1.0f) : 0.f;
  }
  __syncthreads();

  #pragma unroll
  for (int r = 0; r < 4; r++){
    int g = t + 256*r; int e = g >> 4, c = g & 15;
    if (e0 + e >= NEDGE) continue;
    float s = sim_s[e];
    const float4 up = *(const float4*)&in_lds[e*132 + 64 + (c << 2)];
    float* dst = out_ent + (size_t)ii_s[e]*64 + (c << 2);
    atomicAdd(dst+0, s*up.x); atomicAdd(dst+1, s*up.y);
    atomicAdd(dst+2, s*up.z); atomicAdd(dst+3, s*up.w);
  }
}

// ---------------------------------------------------------------------------
// Finals: wave per row, squash_normalize + residual (+ softmax mix for users)
// ---------------------------------------------------------------------------
__global__ __launch_bounds__(256) void k_final_user(
    const float* __restrict__ usr, const float* __restrict__ acc2,
    const float* __restrict__ cnt, const float* __restrict__ w3,
    float* __restrict__ out_user)
{
  const int t = threadIdx.x, lane = t & 63;
  const int u = blockIdx.x*4 + (t >> 6);
  if (u >= NUSR) return;
  float a = w3[0], b = w3[1], c = w3[2];
  float m = fmaxf(a, fmaxf(b, c));
  float ea = expf(a - m), eb = expf(b - m), ec = expf(c - m);
  float es = ea + eb + ec;
  float wsa[3] = { ea/es, eb/es, ec/es };
  float ue = usr[(size_t)u*64 + lane];
  float o = 0.f;
  #pragma unroll
  for (int f = 0; f < 3; f++){
    float dn = fmaxf(cnt[(size_t)f*NUSR + u], 1.0f);
    float v = acc2[((size_t)f*NUSR + u)*64 + lane] / dn;
    float s2 = v*v;
    #pragma unroll
    for (int mk = 1; mk < 64; mk <<= 1) s2 += __shfl_xor(s2, mk);
    float n = sqrtf(s2);
    float fac = (n*n / (n*n + 1.0f)) / fmaxf(n, 1e-12f);
    o += wsa[f] * (fac*v + ue);
  }
  out_user[(size_t)u*64 + lane] = o;
}

__global__ __launch_bounds__(256) void k_final_ent(
    const float* __restrict__ ent, const float* __restrict__ cnt_i,
    float* __restrict__ out_ent)
{
  const int t = threadIdx.x, lane = t & 63;
  const int i = blockIdx.x*4 + (t >> 6);
  if (i >= NENT) return;
  float dn = fmaxf(cnt_i[i], 1.0f);
  size_t off = (size_t)i*64 + lane;
  float v = out_ent[off] / dn;
  float s2 = v*v;
  #pragma unroll
  for (int mk = 1; mk < 64; mk <<= 1) s2 += __shfl_xor(s2, mk);
  float n = sqrtf(s2);
  float fac = (n*n / (n*n + 1.0f)) / fmaxf(n, 1e-12f);
  out_ent[off] = fac*v + ent[off];
}

// ---------------------------------------------------------------------------
// Workspace layout (float element offsets). Total ws need: 272.8 MB.
//   sum_ne  [3*U*64]   @ 0
//   cnt     [3*U]      @ 19,200,000
//   acc2    [3*U*64]   @ 19,500,000
//   sum_up  [ENT*64]   @ 38,700,000
//   cnt_i   [ENT]      @ 51,500,000
//   rtype   [E] (i32)  @ 51,700,000
//   rel16   [E*64]bf16 @ 52,200,000 (byte 208.8M, 64 MB)
// acc2_i lives in d_out's entity region (zeroed each launch).
// ---------------------------------------------------------------------------
extern "C" void kernel_launch(void* const* d_in, const int* in_sizes, int n_in,
                              void* d_out, int out_size, void* d_ws, size_t ws_size,
                              hipStream_t stream) {
  const float* ent = (const float*)d_in[0];
  const float* usr = (const float*)d_in[1];
  const float* lat = (const float*)d_in[2];
  const int*   ui  = (const int*)d_in[3];
  const int*   ii  = (const int*)d_in[4];
  const float* Ww  = (const float*)d_in[5];
  const float* Wb  = (const float*)d_in[6];
  const float* Wiw = (const float*)d_in[7];
  const float* Wib = (const float*)d_in[8];
  const float* w3  = (const float*)d_in[9];

  float* ws  = (float*)d_ws;
  float* out = (float*)d_out;

  float* sum_ne = ws;
  float* cnt    = ws + 19200000ull;
  float* acc2   = ws + 19500000ull;
  float* sum_up = ws + 38700000ull;
  float* cnt_i  = ws + 51500000ull;
  int*   rtype  = (int*)(ws + 51700000ull);
  u16*   rel16  = (u16*)(ws + 52200000ull);

  float* out_ent  = out;                     // entity_agg first (also acc2_i)
  float* out_user = out + (size_t)NENT*64;   // then user_agg

  hipMemsetAsync(ws, 0, 51700000ull*4, stream);           // all accumulators
  hipMemsetAsync(out_ent, 0, (size_t)NENT*64*4, stream);  // acc2_i region

  k_pass1<<<7813, 256, 0, stream>>>(ent, usr, lat, ui, ii, Ww, Wb,
                                    sum_ne, cnt, sum_up, cnt_i, rtype, rel16);
  k_pass2_user<<<31250, 256, 0, stream>>>(ent, ui, ii, sum_ne, cnt, rtype,
                                          rel16, acc2);
  k_pass2_ent<<<7813, 256, 0, stream>>>(ent, usr, ui, ii, Wiw, Wib,
                                        sum_up, cnt_i, out_ent);
  k_final_user<<<25000, 256, 0, stream>>>(usr, acc2, cnt, w3, out_user);
  k_final_ent<<<50000, 256, 0, stream>>>(ent, cnt_i, out_ent);
}

// Round 2
// 1198.044 us; speedup vs baseline: 1.7331x; 1.7331x over previous
//
#include <hip/hip_runtime.h>
#include <stdint.h>

#define NEDGE 500000
#define NUSR  100000
#define NENT  200000

// ---------------------------------------------------------------------------
// CSR build: histogram -> single-block scan -> cursor scatter.
// Replaces ~128M f32 device atomics with ~2M int atomics.
// ---------------------------------------------------------------------------
__global__ __launch_bounds__(256) void k_hist(
    const int* __restrict__ ui, const int* __restrict__ ii,
    int* __restrict__ deg_u, int* __restrict__ deg_i)
{
  int e = blockIdx.x*256 + threadIdx.x;
  if (e >= NEDGE) return;
  atomicAdd(&deg_u[ui[e]], 1);
  atomicAdd(&deg_i[ii[e]], 1);
}

__device__ void scan_arr(const int* __restrict__ deg, int* __restrict__ off,
                         int n, int* wsum)
{
  const int t = threadIdx.x, lane = t & 63, wv = t >> 6;
  int carry = 0;
  for (int base = 0; base < n; base += 8192){
    int loc[8]; int tsum = 0;
    int i0 = base + t*8;
    #pragma unroll
    for (int j = 0; j < 8; j++){
      int i = i0 + j; int v = (i < n) ? deg[i] : 0;
      loc[j] = tsum; tsum += v;
    }
    int x = tsum;                         // inclusive wave scan
    #pragma unroll
    for (int d = 1; d < 64; d <<= 1){
      int y = __shfl_up(x, d);
      if (lane >= d) x += y;
    }
    if (lane == 63) wsum[wv] = x;
    __syncthreads();
    int wpre = 0, tot = 0;
    #pragma unroll
    for (int w2 = 0; w2 < 16; w2++){
      int s = wsum[w2];
      if (w2 < wv) wpre += s;
      tot += s;
    }
    int tbase = carry + wpre + (x - tsum);  // exclusive thread base
    #pragma unroll
    for (int j = 0; j < 8; j++){
      int i = i0 + j;
      if (i < n) off[i] = tbase + loc[j];
    }
    carry += tot;
    __syncthreads();
  }
  if (t == 0) off[n] = carry;
}

__global__ __launch_bounds__(1024) void k_scan(
    const int* __restrict__ deg_u, int* __restrict__ off_u,
    const int* __restrict__ deg_i, int* __restrict__ off_i)
{
  __shared__ int wsum[16];
  scan_arr(deg_u, off_u, NUSR, wsum);
  __syncthreads();
  scan_arr(deg_i, off_i, NENT, wsum);
}

__global__ __launch_bounds__(256) void k_scatter(
    const int* __restrict__ ui, const int* __restrict__ ii,
    const int* __restrict__ off_u, const int* __restrict__ off_i,
    int* __restrict__ cur_u, int* __restrict__ cur_i,
    int* __restrict__ edge_u, int* __restrict__ edge_i)
{
  int e = blockIdx.x*256 + threadIdx.x;
  if (e >= NEDGE) return;
  int u = ui[e]; int p = atomicAdd(&cur_u[u], 1); edge_u[off_u[u] + p] = e;
  int i = ii[e]; int q = atomicAdd(&cur_i[i], 1); edge_i[off_i[i] + q] = e;
}

// ---------------------------------------------------------------------------
// Per-edge 128->64 matvec (f32), leaky_relu, coalesced f32 relation store.
// WITH_ARGMAX: also scores vs latent_emb -> rtype.  No scatter atomics.
// Block: 256 threads, 64 edges. Thread (og,eg) owns edges {eg+16i}, outs {og+16j}.
// ---------------------------------------------------------------------------
template<int WITH_ARGMAX>
__global__ __launch_bounds__(256,2) void k_matvec(
    const float* __restrict__ rowsA, const float* __restrict__ rowsB,
    const int* __restrict__ idxA, const int* __restrict__ idxB,
    const float* __restrict__ lat,
    const float* __restrict__ Ww, const float* __restrict__ Wb,
    float* __restrict__ rel, int* __restrict__ rtype)
{
  __shared__ __align__(16) float w_lds[64*132];
  __shared__ __align__(16) float in_lds[64*132];   // reused as f32 rel transpose
  __shared__ float lat_lds[192];
  __shared__ float b_lds[64];
  __shared__ int ia_s[64], ib_s[64];
  __shared__ float part[4*64*3];

  const int t  = threadIdx.x;
  const int e0 = blockIdx.x * 64;

  // A: stage W (64x128), bias, latent, edge indices
  #pragma unroll
  for (int r = 0; r < 8; r++){
    int g = t + 256*r; int row = g >> 5, c4 = (g & 31) << 2;
    *(float4*)&w_lds[row*132 + c4] = *(const float4*)(Ww + row*128 + c4);
  }
  if (WITH_ARGMAX && t < 192) lat_lds[t] = lat[t];
  if (t < 64){
    b_lds[t] = Wb[t];
    int e = e0 + t;
    ia_s[t] = (e < NEDGE) ? idxA[e] : 0;
    ib_s[t] = (e < NEDGE) ? idxB[e] : 0;
  }
  __syncthreads();

  // B: gather concat([rowsA, rowsB]) rows
  #pragma unroll
  for (int r = 0; r < 8; r++){
    int g = t + 256*r; int e = g >> 5, c = g & 31;
    float4 v;
    if (e0 + e < NEDGE){
      const float* src = (c < 16) ? (rowsA + (size_t)ia_s[e]*64 + (c << 2))
                                  : (rowsB + (size_t)ib_s[e]*64 + ((c-16) << 2));
      v = *(const float4*)src;
    } else v = make_float4(0.f,0.f,0.f,0.f);
    *(float4*)&in_lds[e*132 + (c << 2)] = v;
  }
  __syncthreads();

  // C: 128->64 matvec, 4 edges x 4 outs per thread
  const int og = t >> 4, eg = t & 15;
  float acc[4][4];
  #pragma unroll
  for (int i = 0; i < 4; i++)
    #pragma unroll
    for (int j = 0; j < 4; j++) acc[i][j] = b_lds[og + 16*j];
  for (int k = 0; k < 128; k += 4){
    float4 av[4], wv[4];
    #pragma unroll
    for (int i = 0; i < 4; i++) av[i] = *(const float4*)&in_lds[(eg+16*i)*132 + k];
    #pragma unroll
    for (int j = 0; j < 4; j++) wv[j] = *(const float4*)&w_lds[(og+16*j)*132 + k];
    #pragma unroll
    for (int i = 0; i < 4; i++)
      #pragma unroll
      for (int j = 0; j < 4; j++)
        acc[i][j] += av[i].x*wv[j].x + av[i].y*wv[j].y + av[i].z*wv[j].z + av[i].w*wv[j].w;
  }
  #pragma unroll
  for (int i = 0; i < 4; i++)
    #pragma unroll
    for (int j = 0; j < 4; j++){
      float v = acc[i][j];
      acc[i][j] = v > 0.f ? v : 0.01f*v;   // leaky_relu(0.01)
    }

  // scores vs latent (registers + cross-lane), before in_lds is clobbered
  float p[4][3];
  if (WITH_ARGMAX){
    #pragma unroll
    for (int i = 0; i < 4; i++)
      #pragma unroll
      for (int f = 0; f < 3; f++){
        float s = 0.f;
        #pragma unroll
        for (int j = 0; j < 4; j++) s += acc[i][j] * lat_lds[f*64 + og + 16*j];
        s += __shfl_xor(s, 16);
        s += __shfl_xor(s, 32);
        p[i][f] = s;
      }
  }
  __syncthreads();                        // matvec reads of in_lds complete

  // transpose acc -> in_lds (stride 68: 16B-aligned rows, 2-way banks = free)
  float* relbuf = in_lds;
  #pragma unroll
  for (int i = 0; i < 4; i++)
    #pragma unroll
    for (int j = 0; j < 4; j++)
      relbuf[(eg+16*i)*68 + og + 16*j] = acc[i][j];
  if (WITH_ARGMAX && (t & 63) < 16){
    int wv = t >> 6;
    #pragma unroll
    for (int i = 0; i < 4; i++)
      #pragma unroll
      for (int f = 0; f < 3; f++)
        part[(wv*64 + eg + 16*i)*3 + f] = p[i][f];
  }
  __syncthreads();

  // coalesced f32x4 relation store
  #pragma unroll
  for (int r = 0; r < 4; r++){
    int g = t + 256*r; int e = g >> 4, c = g & 15;
    if (e0 + e < NEDGE)
      *(float4*)(rel + (size_t)(e0+e)*64 + (c << 2)) =
          *(const float4*)&relbuf[e*68 + (c << 2)];
  }

  if (WITH_ARGMAX && t < 64 && e0 + t < NEDGE){
    float s0 = part[t*3+0] + part[(64+t)*3+0] + part[(128+t)*3+0] + part[(192+t)*3+0];
    float s1 = part[t*3+1] + part[(64+t)*3+1] + part[(128+t)*3+1] + part[(192+t)*3+1];
    float s2 = part[t*3+2] + part[(64+t)*3+2] + part[(128+t)*3+2] + part[(192+t)*3+2];
    int bf = 0; float bs = s0;
    if (s1 > bs){ bs = s1; bf = 1; }     // strict > : first-max ties like jnp.argmax
    if (s2 > bs){ bs = s2; bf = 2; }
    rtype[e0 + t] = bf;
  }
}

// ---------------------------------------------------------------------------
// User side, one wave per user: both reduction levels + squash + softmax mix.
// Zero atomics, zero LDS. lane = embedding dim.
// ---------------------------------------------------------------------------
__global__ __launch_bounds__(256) void k_user(
    const float* __restrict__ ent, const float* __restrict__ usr,
    const float* __restrict__ w3,
    const int* __restrict__ iidx, const int* __restrict__ rtype,
    const float* __restrict__ rel,
    const int* __restrict__ off_u, const int* __restrict__ edge_u,
    float* __restrict__ out_user)
{
  const int lane = threadIdx.x & 63;
  const int u = blockIdx.x*4 + (threadIdx.x >> 6);
  if (u >= NUSR) return;
  const int beg = off_u[u], end = off_u[u+1];

  float s0=0.f, s1=0.f, s2=0.f; int c0=0, c1=0, c2=0;
  for (int k = beg; k < end; k++){
    int e = edge_u[k];
    int f = rtype[e];
    float ip = ent[(size_t)iidx[e]*64 + lane];
    if (f == 0){ s0 += ip; c0++; }
    else if (f == 1){ s1 += ip; c1++; }
    else { s2 += ip; c2++; }
  }
  const float d0 = fmaxf((float)c0, 1.f);
  const float d1 = fmaxf((float)c1, 1.f);
  const float d2 = fmaxf((float)c2, 1.f);

  float a0=0.f, a1=0.f, a2=0.f;
  for (int k = beg; k < end; k++){
    int e = edge_u[k];
    int f = rtype[e];
    float ip = ent[(size_t)iidx[e]*64 + lane];
    float rv = rel[(size_t)e*64 + lane];
    float ss = (f == 0) ? s0 : ((f == 1) ? s1 : s2);
    float dd = (f == 0) ? d0 : ((f == 1) ? d1 : d2);
    float p = rv * ss;
    #pragma unroll
    for (int m = 1; m < 64; m <<= 1) p += __shfl_xor(p, m);
    float sim = p / dd;                  // dot(rel, u_) with mean folded in
    if (f == 0) a0 += sim*ip; else if (f == 1) a1 += sim*ip; else a2 += sim*ip;
  }

  float wa = w3[0], wb = w3[1], wc = w3[2];
  float mx = fmaxf(wa, fmaxf(wb, wc));
  float ea = expf(wa-mx), eb = expf(wb-mx), ec = expf(wc-mx);
  float inv = 1.f/(ea+eb+ec);
  float ue = usr[(size_t)u*64 + lane];
  float av[3] = {a0,a1,a2}, dv[3] = {d0,d1,d2}, wv[3] = {ea*inv, eb*inv, ec*inv};
  float o = 0.f;
  #pragma unroll
  for (int f = 0; f < 3; f++){
    float v = av[f]/dv[f];
    float n2 = v*v;
    #pragma unroll
    for (int m = 1; m < 64; m <<= 1) n2 += __shfl_xor(n2, m);
    float n = sqrtf(n2);
    float fac = (n2/(n2 + 1.f)) / fmaxf(n, 1e-12f);
    o += wv[f]*(fac*v + ue);
  }
  out_user[(size_t)u*64 + lane] = o;
}

// ---------------------------------------------------------------------------
// Entity side, one wave per entity: sum_up -> sim_i -> y -> squash + residual.
// ---------------------------------------------------------------------------
__global__ __launch_bounds__(256) void k_ent(
    const float* __restrict__ ent, const float* __restrict__ usr,
    const int* __restrict__ uidx, const float* __restrict__ rel,
    const int* __restrict__ off_i, const int* __restrict__ edge_i,
    float* __restrict__ out_ent)
{
  const int lane = threadIdx.x & 63;
  const int i = blockIdx.x*4 + (threadIdx.x >> 6);
  if (i >= NENT) return;
  const int beg = off_i[i], end = off_i[i+1];

  float s = 0.f;
  for (int k = beg; k < end; k++){
    int e = edge_i[k];
    s += usr[(size_t)uidx[e]*64 + lane];
  }
  const float d = fmaxf((float)(end - beg), 1.f);

  float a = 0.f;
  for (int k = beg; k < end; k++){
    int e = edge_i[k];
    float up = usr[(size_t)uidx[e]*64 + lane];
    float rv = rel[(size_t)e*64 + lane];
    float p = rv * s;
    #pragma unroll
    for (int m = 1; m < 64; m <<= 1) p += __shfl_xor(p, m);
    a += (p/d)*up;
  }
  float v = a/d;
  float n2 = v*v;
  #pragma unroll
  for (int m = 1; m < 64; m <<= 1) n2 += __shfl_xor(n2, m);
  float n = sqrtf(n2);
  float fac = (n2/(n2 + 1.f)) / fmaxf(n, 1e-12f);
  out_ent[(size_t)i*64 + lane] = fac*v + ent[(size_t)i*64 + lane];
}

// ---------------------------------------------------------------------------
// Workspace layout (float/int element offsets). Total: 265.6 MB.
//   rel_ui f32 [E*64]      @ 0            (128 MB)
//   rel_iu f32 [E*64]      @ 32,000,000   (128 MB)
//   rtype      [E]         @ 64,000,000
//   zero-block             @ 64,500,000:  deg_u(100k) cur_u(100k) deg_i(200k) cur_i(200k)
//   off_u      [U+1]       @ 65,100,000
//   off_i      [ENT+1]     @ 65,200,004
//   edge_u     [E]         @ 65,400,008
//   edge_i     [E]         @ 65,900,008
// ---------------------------------------------------------------------------
extern "C" void kernel_launch(void* const* d_in, const int* in_sizes, int n_in,
                              void* d_out, int out_size, void* d_ws, size_t ws_size,
                              hipStream_t stream) {
  const float* ent = (const float*)d_in[0];
  const float* usr = (const float*)d_in[1];
  const float* lat = (const float*)d_in[2];
  const int*   ui  = (const int*)d_in[3];
  const int*   ii  = (const int*)d_in[4];
  const float* Ww  = (const float*)d_in[5];
  const float* Wb  = (const float*)d_in[6];
  const float* Wiw = (const float*)d_in[7];
  const float* Wib = (const float*)d_in[8];
  const float* w3  = (const float*)d_in[9];

  float* ws = (float*)d_ws;
  float* rel_ui = ws;
  float* rel_iu = ws + 32000000ull;
  int*   rtype  = (int*)(ws + 64000000ull);
  int*   deg_u  = (int*)(ws + 64500000ull);
  int*   cur_u  = deg_u + 100000;
  int*   deg_i  = cur_u + 100000;
  int*   cur_i  = deg_i + 200000;
  int*   off_u  = (int*)(ws + 65100000ull);
  int*   off_i  = (int*)(ws + 65200004ull);
  int*   edge_u = (int*)(ws + 65400008ull);
  int*   edge_i = (int*)(ws + 65900008ull);

  float* out_ent  = (float*)d_out;
  float* out_user = (float*)d_out + (size_t)NENT*64;

  hipMemsetAsync(deg_u, 0, 600000*sizeof(int), stream);   // deg+cur, both sides

  k_hist<<<1954, 256, 0, stream>>>(ui, ii, deg_u, deg_i);
  k_scan<<<1, 1024, 0, stream>>>(deg_u, off_u, deg_i, off_i);
  k_scatter<<<1954, 256, 0, stream>>>(ui, ii, off_u, off_i,
                                      cur_u, cur_i, edge_u, edge_i);

  // relation_ui = leaky(concat([user, item]) @ Ww^T + b), + argmax -> rtype
  k_matvec<1><<<7813, 256, 0, stream>>>(usr, ent, ui, ii, lat, Ww, Wb,
                                        rel_ui, rtype);
  // relation_iu = leaky(concat([item, user]) @ Wiw^T + b)
  k_matvec<0><<<7813, 256, 0, stream>>>(ent, usr, ii, ui, lat, Wiw, Wib,
                                        rel_iu, rtype);

  k_user<<<25000, 256, 0, stream>>>(ent, usr, w3, ii, rtype, rel_ui,
                                    off_u, edge_u, out_user);
  k_ent<<<50000, 256, 0, stream>>>(ent, usr, ui, rel_iu,
                                   off_i, edge_i, out_ent);
}